// Round 11
// baseline (158.808 us; speedup 1.0000x reference)
//
#include <hip/hip_runtime.h>
#include <hip/hip_bf16.h>

typedef __attribute__((ext_vector_type(4))) float  f32x4;
typedef __attribute__((ext_vector_type(8))) short  short8;
typedef unsigned int u32;

#define EMBED 4096
#define LR    512
#define KSEL  128
#define BATCH 8192

__device__ __forceinline__ short f2bf(float x) {
  union { float f; unsigned u; } c; c.f = x;
  unsigned r = c.u + 0x7FFFu + ((c.u >> 16) & 1u);  // RNE
  return (short)(r >> 16);
}
__device__ __forceinline__ void gload16(const void* g, void* l) {
  __builtin_amdgcn_global_load_lds((const __attribute__((address_space(1))) u32*)g,
                                   (__attribute__((address_space(3))) u32*)l, 16, 0, 0);
}

// K0: gather selected columns of W, emit two bf16 MFMA-packed layouts.
// Wp : [e/8][128 cols][8]  (B-operand for GEMM1: kk-dim = embed)
// Wtp: [c/8][4096 e ][8]  (B-operand for GEMM2: kk-dim = sel index)
__global__ __launch_bounds__(256) void pack_w_kernel(
    const float* __restrict__ W, const int* __restrict__ sel,
    short* __restrict__ Wp, short* __restrict__ Wtp) {
  int idx = blockIdx.x * 256 + threadIdx.x;
  int e = idx >> 7;
  int c = idx & 127;
  int r = sel[c];
  short v = f2bf(W[e * LR + r]);
  Wp [(((e >> 3) << 7) + c) * 8 + (e & 7)] = v;
  Wtp[(((c >> 3) << 12) + e) * 8 + (c & 7)] = v;
}

// DIFF: Dp (row-major bf16 [8192][4096]) = bf16(src - base).
// Copy-bench shape: grid-stride, 2048x256, 32 waves/CU, wave reads 2KB
// contiguous per array per iter, writes 1KB contiguous. This is the
// decisive probe: its rate = the true ceiling for streaming base+src.
__global__ __launch_bounds__(256) void diff_kernel(
    const float* __restrict__ base, const float* __restrict__ src,
    short* __restrict__ Dp) {
  const size_t nchunks = (size_t)BATCH * EMBED / 8;   // 4,194,304
  const size_t stride  = (size_t)gridDim.x * 256;
  for (size_t i = (size_t)blockIdx.x * 256 + threadIdx.x; i < nchunks; i += stride) {
    const float* b = base + i * 8;
    const float* s = src  + i * 8;
    f32x4 b0 = *(const f32x4*)b;
    f32x4 b1 = *(const f32x4*)(b + 4);
    f32x4 s0 = *(const f32x4*)s;
    f32x4 s1 = *(const f32x4*)(s + 4);
    union { short8 v; __hip_bfloat162 h[4]; } u;
    u.h[0] = __float22bfloat162_rn(make_float2(s0[0] - b0[0], s0[1] - b0[1]));
    u.h[1] = __float22bfloat162_rn(make_float2(s0[2] - b0[2], s0[3] - b0[3]));
    u.h[2] = __float22bfloat162_rn(make_float2(s1[0] - b1[0], s1[1] - b1[1]));
    u.h[3] = __float22bfloat162_rn(make_float2(s1[2] - b1[2], s1[3] - b1[3]));
    *(short8*)(Dp + i * 8) = u.v;
  }
}

// K1b: Tp (packed bf16 [kk/8][8192][8]) = Dp @ Wsel   (Dp is bf16, L3-hot)
// R8 staging structure at 1/4 the bytes: 512 blocks x 256 thr (4 waves),
// block = 16 rows x full K. BK=256 (8KB/buf, 16 steps, 2 gload16/thread).
// LDS chunk XOR-swizzle via pre-swizzled source (rule 21); B-frags from
// L2-resident Wp issued before STAGE. No f32->bf16 cvt needed in-loop.
__global__ __launch_bounds__(256, 3) void gemm1b_kernel(
    const short* __restrict__ Dp, const short* __restrict__ Wp,
    short* __restrict__ Tp) {
  __shared__ __align__(16) char smem[16384];   // 2 bufs x (16 rows x 512B)
  const int t  = threadIdx.x;
  const int w  = t >> 6, l = t & 63;
  const int lr = l & 15, lg = l >> 4;
  const int row0 = blockIdx.x * 16;

  // staging: thread t -> dest chunks t and t+256 (16B each), layout
  // [row][32 slots]; slot holds source chunk slot^(row&7).
  const int r0 = t >> 5,         c0 = t & 31;
  const int r1 = (t + 256) >> 5, c1 = t & 31;
  const short* g0 = Dp + (size_t)(row0 + r0) * EMBED + ((c0 ^ (r0 & 7)) << 3);
  const short* g1 = Dp + (size_t)(row0 + r1) * EMBED + ((c1 ^ (r1 & 7)) << 3);

  #define STAGE(s, b) do {                        \
    char* d_ = smem + (b) * 8192 + t * 16;        \
    gload16(g0 + (s) * 256, d_);                  \
    gload16(g1 + (s) * 256, d_ + 4096);           \
  } while (0)

  const short8* wq = (const short8*)Wp;
  f32x4 acc0 = {0.f, 0.f, 0.f, 0.f}, acc1 = {0.f, 0.f, 0.f, 0.f};

  STAGE(0, 0);
  int b = 0;
  for (int s = 0; s < 16; ++s) {
    __syncthreads();                         // buf b staged
    const int kc = s * 256;
    short8 bf[16];                           // B-frags first (older in queue)
    #pragma unroll
    for (int kstep = 0; kstep < 8; ++kstep) {
      const int kg = ((kc + kstep * 32) >> 3) + lg;
      bf[kstep * 2]     = wq[(size_t)kg * 128 + w * 32 + lr];
      bf[kstep * 2 + 1] = wq[(size_t)kg * 128 + w * 32 + 16 + lr];
    }
    if (s < 15) STAGE(s + 1, b ^ 1);         // flies under this step's compute
    const char* tb = smem + b * 8192 + lr * 512;
    #pragma unroll
    for (int kstep = 0; kstep < 8; ++kstep) {
      const int c = (kstep * 4 + lg) ^ (lr & 7);
      short8 a = *(const short8*)(tb + c * 16);
      acc0 = __builtin_amdgcn_mfma_f32_16x16x32_bf16(a, bf[kstep * 2],     acc0, 0, 0, 0);
      acc1 = __builtin_amdgcn_mfma_f32_16x16x32_bf16(a, bf[kstep * 2 + 1], acc1, 0, 0, 0);
    }
    b ^= 1;
  }
  #undef STAGE

  // lane holds T[row0 + 4lg + r][kk = w*32 + ct*16 + lr]
  #pragma unroll
  for (int ct = 0; ct < 2; ++ct) {
    f32x4 a = ct ? acc1 : acc0;
    const int kk = w * 32 + ct * 16 + lr;
    short* dst = Tp + (size_t)(((kk >> 3) << 13) + row0 + (lg << 2)) * 8 + (kk & 7);
    #pragma unroll
    for (int r = 0; r < 4; ++r) dst[r * 8] = f2bf(a[r]);
  }
}

// K1 FALLBACK (R8 form, reads base/src directly) if workspace is too small.
__global__ __launch_bounds__(256, 2) void gemm1_kernel(
    const float* __restrict__ base, const float* __restrict__ src,
    const short* __restrict__ Wp, short* __restrict__ Tp) {
  __shared__ __align__(16) char smem[65536];
  const int t  = threadIdx.x;
  const int w  = t >> 6, l = t & 63;
  const int lr = l & 15, lg = l >> 4;
  const int row0 = blockIdx.x * 16;
  const int srow = t >> 6;
  const int sc   = t & 63;

  #define STAGE(s, b) do {                                                  \
    char* d_ = smem + (b) * 32768 + t * 16;                                 \
    _Pragma("unroll")                                                       \
    for (int i = 0; i < 4; ++i) {                                           \
      const int row = i * 4 + srow;                                         \
      const size_t go = (size_t)(row0 + row) * EMBED + (s) * 256            \
                        + ((sc ^ (row & 7)) << 2);                          \
      gload16(base + go, d_ + i * 4096);                                    \
      gload16(src  + go, d_ + 16384 + i * 4096);                            \
    }                                                                       \
  } while (0)

  const short8* wq = (const short8*)Wp;
  f32x4 acc0 = {0.f, 0.f, 0.f, 0.f}, acc1 = {0.f, 0.f, 0.f, 0.f};

  STAGE(0, 0);
  int b = 0;
  for (int s = 0; s < 16; ++s) {
    __syncthreads();
    const int kc = s * 256;
    short8 bf[16];
    #pragma unroll
    for (int kstep = 0; kstep < 8; ++kstep) {
      const int kg = ((kc + kstep * 32) >> 3) + lg;
      bf[kstep * 2]     = wq[(size_t)kg * 128 + w * 32 + lr];
      bf[kstep * 2 + 1] = wq[(size_t)kg * 128 + w * 32 + 16 + lr];
    }
    if (s < 15) STAGE(s + 1, b ^ 1);
    const char* tb = smem + b * 32768 + lr * 1024;
    #pragma unroll
    for (int kstep = 0; kstep < 8; ++kstep) {
      const int j0 = (kstep * 8 + lg * 2)     ^ (lr & 7);
      const int j1 = (kstep * 8 + lg * 2 + 1) ^ (lr & 7);
      f32x4 b0 = *(const f32x4*)(tb + j0 * 16);
      f32x4 b1 = *(const f32x4*)(tb + j1 * 16);
      f32x4 s0 = *(const f32x4*)(tb + 16384 + j0 * 16);
      f32x4 s1 = *(const f32x4*)(tb + 16384 + j1 * 16);
      union { short8 v; __hip_bfloat162 h[4]; } u;
      u.h[0] = __float22bfloat162_rn(make_float2(s0[0] - b0[0], s0[1] - b0[1]));
      u.h[1] = __float22bfloat162_rn(make_float2(s0[2] - b0[2], s0[3] - b0[3]));
      u.h[2] = __float22bfloat162_rn(make_float2(s1[0] - b1[0], s1[1] - b1[1]));
      u.h[3] = __float22bfloat162_rn(make_float2(s1[2] - b1[2], s1[3] - b1[3]));
      acc0 = __builtin_amdgcn_mfma_f32_16x16x32_bf16(u.v, bf[kstep * 2],     acc0, 0, 0, 0);
      acc1 = __builtin_amdgcn_mfma_f32_16x16x32_bf16(u.v, bf[kstep * 2 + 1], acc1, 0, 0, 0);
    }
    b ^= 1;
  }
  #undef STAGE

  #pragma unroll
  for (int ct = 0; ct < 2; ++ct) {
    f32x4 a = ct ? acc1 : acc0;
    const int kk = w * 32 + ct * 16 + lr;
    short* dst = Tp + (size_t)(((kk >> 3) << 13) + row0 + (lg << 2)) * 8 + (kk & 7);
    #pragma unroll
    for (int r = 0; r < 4; ++r) dst[r * 8] = f2bf(a[r]);
  }
}

// K2: out = base + T @ Wsel^T. Block: 64 rows x 256 cols, 4 waves.
__global__ __launch_bounds__(256) void gemm2_kernel(
    const float* __restrict__ base, const short* __restrict__ Tp,
    const short* __restrict__ Wtp, float* __restrict__ out) {
  const int t  = threadIdx.x;
  const int w  = t >> 6, l = t & 63;
  const int lr = l & 15, lg = l >> 4;
  const int mt = blockIdx.x >> 4, nt = blockIdx.x & 15;
  const int row0 = mt * 64;
  const int col0 = nt * 256 + w * 64;

  short8 afr[4][4];
  #pragma unroll
  for (int m = 0; m < 4; ++m)
    #pragma unroll
    for (int ks = 0; ks < 4; ++ks)
      afr[m][ks] = *(const short8*)(Tp + (size_t)(((ks * 4 + lg) << 13) + row0 + m * 16 + lr) * 8);

  f32x4 acc[4][4];
  #pragma unroll
  for (int m = 0; m < 4; ++m)
    #pragma unroll
    for (int nf = 0; nf < 4; ++nf) acc[m][nf] = (f32x4){0.f, 0.f, 0.f, 0.f};

  #pragma unroll
  for (int nf = 0; nf < 4; ++nf) {
    short8 bfr[4];
    #pragma unroll
    for (int ks = 0; ks < 4; ++ks)
      bfr[ks] = *(const short8*)(Wtp + (size_t)(((ks * 4 + lg) << 12) + col0 + nf * 16 + lr) * 8);
    #pragma unroll
    for (int m = 0; m < 4; ++m)
      #pragma unroll
      for (int ks = 0; ks < 4; ++ks)
        acc[m][nf] = __builtin_amdgcn_mfma_f32_16x16x32_bf16(afr[m][ks], bfr[ks], acc[m][nf], 0, 0, 0);
  }

  #pragma unroll
  for (int m = 0; m < 4; ++m)
    #pragma unroll
    for (int r = 0; r < 4; ++r) {
      const size_t row = row0 + m * 16 + lg * 4 + r;
      #pragma unroll
      for (int nf = 0; nf < 4; ++nf) {
        const size_t o = row * EMBED + col0 + nf * 16 + lr;
        out[o] = base[o] + acc[m][nf][r];
      }
    }
}

extern "C" void kernel_launch(void* const* d_in, const int* in_sizes, int n_in,
                              void* d_out, int out_size, void* d_ws, size_t ws_size,
                              hipStream_t stream) {
  const float* base = (const float*)d_in[0];
  const float* src  = (const float*)d_in[1];
  const int*   sub  = (const int*)d_in[2];
  const float* W    = (const float*)d_in[3];
  float* out = (float*)d_out;

  short* Wp  = (short*)d_ws;                       // 1 MB
  short* Wtp = Wp  + EMBED * KSEL;                 // 1 MB
  short* Tp  = Wtp + EMBED * KSEL;                 // 2 MB
  short* Dp  = Tp  + BATCH * KSEL;                 // 64 MB (offset 4 MB)

  pack_w_kernel<<<EMBED * KSEL / 256, 256, 0, stream>>>(W, sub, Wp, Wtp);

  const size_t need = (size_t)4 * 1024 * 1024 + (size_t)BATCH * EMBED * 2;
  if (ws_size >= need) {
    diff_kernel<<<2048, 256, 0, stream>>>(base, src, Dp);
    gemm1b_kernel<<<BATCH / 16, 256, 0, stream>>>(Dp, Wp, Tp);
  } else {
    gemm1_kernel<<<BATCH / 16, 256, 0, stream>>>(base, src, Wp, Tp);
  }

  gemm2_kernel<<<(BATCH / 64) * 16, 256, 0, stream>>>(base, Tp, Wtp, out);
}

// Round 12
// 120.094 us; speedup vs baseline: 1.3224x; 1.3224x over previous
//
#include <hip/hip_runtime.h>
#include <hip/hip_bf16.h>

typedef __attribute__((ext_vector_type(4))) float  f32x4;
typedef __attribute__((ext_vector_type(8))) short  short8;
typedef unsigned int u32;

#define EMBED 4096
#define LR    512
#define KSEL  128
#define BATCH 8192

__device__ __forceinline__ short f2bf(float x) {
  union { float f; unsigned u; } c; c.f = x;
  unsigned r = c.u + 0x7FFFu + ((c.u >> 16) & 1u);  // RNE
  return (short)(r >> 16);
}
__device__ __forceinline__ void gload16(const void* g, void* l) {
  __builtin_amdgcn_global_load_lds((const __attribute__((address_space(1))) u32*)g,
                                   (__attribute__((address_space(3))) u32*)l, 16, 0, 0);
}

// K0: gather selected columns of W, emit two bf16 MFMA-packed layouts.
// Wp : [e/8][128 cols][8]  (B-operand for GEMM1: kk-dim = embed)
// Wtp: [c/8][4096 e ][8]  (B-operand for GEMM2: kk-dim = sel index)
__global__ __launch_bounds__(256) void pack_w_kernel(
    const float* __restrict__ W, const int* __restrict__ sel,
    short* __restrict__ Wp, short* __restrict__ Wtp) {
  int idx = blockIdx.x * 256 + threadIdx.x;
  int e = idx >> 7;
  int c = idx & 127;
  int r = sel[c];
  short v = f2bf(W[e * LR + r]);
  Wp [(((e >> 3) << 7) + c) * 8 + (e & 7)] = v;
  Wtp[(((c >> 3) << 12) + e) * 8 + (c & 7)] = v;
}

// K1: Tp (packed bf16 [kk/8][8192][8]) = (src - base) @ Wsel
// R8 structure (proven correct, ~103 us standalone). The round-12 change is
// NOT here — it is gemm2's nontemporal out-store, which stops the 128 MB
// out-write from evicting base/src from L3 between graph replays. If the
// pollution theory holds, this kernel's FETCH_SIZE drops 135 MB -> <60 MB
// and its duration falls toward the L3-read bound.
__global__ __launch_bounds__(256, 2) void gemm1_kernel(
    const float* __restrict__ base, const float* __restrict__ src,
    const short* __restrict__ Wp, short* __restrict__ Tp) {
  __shared__ __align__(16) char smem[65536];   // 2 bufs x (16 rows x 1KB x 2 arr)
  const int t  = threadIdx.x;
  const int w  = t >> 6, l = t & 63;
  const int lr = l & 15, lg = l >> 4;
  const int row0 = blockIdx.x * 16;
  const int srow = t >> 6;       // base row (0..3), +4 per issue
  const int sc   = t & 63;       // 16B chunk within a 1KB row-slice

  #define STAGE(s, b) do {                                                  \
    char* d_ = smem + (b) * 32768 + t * 16;                                 \
    _Pragma("unroll")                                                       \
    for (int i = 0; i < 4; ++i) {                                           \
      const int row = i * 4 + srow;                                         \
      const size_t go = (size_t)(row0 + row) * EMBED + (s) * 256            \
                        + ((sc ^ (row & 7)) << 2);                          \
      gload16(base + go, d_ + i * 4096);                                    \
      gload16(src  + go, d_ + 16384 + i * 4096);                            \
    }                                                                       \
  } while (0)

  const short8* wq = (const short8*)Wp;
  f32x4 acc0 = {0.f, 0.f, 0.f, 0.f}, acc1 = {0.f, 0.f, 0.f, 0.f};

  STAGE(0, 0);
  int b = 0;
  for (int s = 0; s < 16; ++s) {
    __syncthreads();                         // buf b staged
    const int kc = s * 256;
    short8 bf[16];                           // B-frags first (older in queue)
    #pragma unroll
    for (int kstep = 0; kstep < 8; ++kstep) {
      const int kg = ((kc + kstep * 32) >> 3) + lg;
      bf[kstep * 2]     = wq[(size_t)kg * 128 + w * 32 + lr];
      bf[kstep * 2 + 1] = wq[(size_t)kg * 128 + w * 32 + 16 + lr];
    }
    if (s < 15) STAGE(s + 1, b ^ 1);         // flies under this step's compute
    const char* tb = smem + b * 32768 + lr * 1024;
    #pragma unroll
    for (int kstep = 0; kstep < 8; ++kstep) {
      const int j0 = (kstep * 8 + lg * 2)     ^ (lr & 7);
      const int j1 = (kstep * 8 + lg * 2 + 1) ^ (lr & 7);
      f32x4 b0 = *(const f32x4*)(tb + j0 * 16);
      f32x4 b1 = *(const f32x4*)(tb + j1 * 16);
      f32x4 s0 = *(const f32x4*)(tb + 16384 + j0 * 16);
      f32x4 s1 = *(const f32x4*)(tb + 16384 + j1 * 16);
      union { short8 v; __hip_bfloat162 h[4]; } u;
      u.h[0] = __float22bfloat162_rn(make_float2(s0[0] - b0[0], s0[1] - b0[1]));
      u.h[1] = __float22bfloat162_rn(make_float2(s0[2] - b0[2], s0[3] - b0[3]));
      u.h[2] = __float22bfloat162_rn(make_float2(s1[0] - b1[0], s1[1] - b1[1]));
      u.h[3] = __float22bfloat162_rn(make_float2(s1[2] - b1[2], s1[3] - b1[3]));
      acc0 = __builtin_amdgcn_mfma_f32_16x16x32_bf16(u.v, bf[kstep * 2],     acc0, 0, 0, 0);
      acc1 = __builtin_amdgcn_mfma_f32_16x16x32_bf16(u.v, bf[kstep * 2 + 1], acc1, 0, 0, 0);
    }
    b ^= 1;
  }
  #undef STAGE

  // lane holds T[row0 + 4lg + r][kk = w*32 + ct*16 + lr]
  #pragma unroll
  for (int ct = 0; ct < 2; ++ct) {
    f32x4 a = ct ? acc1 : acc0;
    const int kk = w * 32 + ct * 16 + lr;
    short* dst = Tp + (size_t)(((kk >> 3) << 13) + row0 + (lg << 2)) * 8 + (kk & 7);
    #pragma unroll
    for (int r = 0; r < 4; ++r) dst[r * 8] = f2bf(a[r]);
  }
}

// K2: out = base + T @ Wsel^T. Block: 64 rows x 256 cols, 4 waves.
// ROUND-12 CHANGE: out stores are NONTEMPORAL (no L3 allocation) so the
// 128 MB output stream stops evicting base/src between replays.
__global__ __launch_bounds__(256) void gemm2_kernel(
    const float* __restrict__ base, const short* __restrict__ Tp,
    const short* __restrict__ Wtp, float* __restrict__ out) {
  const int t  = threadIdx.x;
  const int w  = t >> 6, l = t & 63;
  const int lr = l & 15, lg = l >> 4;
  const int mt = blockIdx.x >> 4, nt = blockIdx.x & 15;
  const int row0 = mt * 64;
  const int col0 = nt * 256 + w * 64;

  short8 afr[4][4];
  #pragma unroll
  for (int m = 0; m < 4; ++m)
    #pragma unroll
    for (int ks = 0; ks < 4; ++ks)
      afr[m][ks] = *(const short8*)(Tp + (size_t)(((ks * 4 + lg) << 13) + row0 + m * 16 + lr) * 8);

  f32x4 acc[4][4];
  #pragma unroll
  for (int m = 0; m < 4; ++m)
    #pragma unroll
    for (int nf = 0; nf < 4; ++nf) acc[m][nf] = (f32x4){0.f, 0.f, 0.f, 0.f};

  #pragma unroll
  for (int nf = 0; nf < 4; ++nf) {
    short8 bfr[4];
    #pragma unroll
    for (int ks = 0; ks < 4; ++ks)
      bfr[ks] = *(const short8*)(Wtp + (size_t)(((ks * 4 + lg) << 12) + col0 + nf * 16 + lr) * 8);
    #pragma unroll
    for (int m = 0; m < 4; ++m)
      #pragma unroll
      for (int ks = 0; ks < 4; ++ks)
        acc[m][nf] = __builtin_amdgcn_mfma_f32_16x16x32_bf16(afr[m][ks], bfr[ks], acc[m][nf], 0, 0, 0);
  }

  #pragma unroll
  for (int m = 0; m < 4; ++m)
    #pragma unroll
    for (int r = 0; r < 4; ++r) {
      const size_t row = row0 + m * 16 + lg * 4 + r;
      #pragma unroll
      for (int nf = 0; nf < 4; ++nf) {
        const size_t o = row * EMBED + col0 + nf * 16 + lr;
        float v = base[o] + acc[m][nf][r];
        __builtin_nontemporal_store(v, &out[o]);
      }
    }
}

extern "C" void kernel_launch(void* const* d_in, const int* in_sizes, int n_in,
                              void* d_out, int out_size, void* d_ws, size_t ws_size,
                              hipStream_t stream) {
  const float* base = (const float*)d_in[0];
  const float* src  = (const float*)d_in[1];
  const int*   sub  = (const int*)d_in[2];
  const float* W    = (const float*)d_in[3];
  float* out = (float*)d_out;

  short* Wp  = (short*)d_ws;                       // 1 MB
  short* Wtp = Wp  + EMBED * KSEL;                 // 1 MB
  short* Tp  = Wtp + EMBED * KSEL;                 // 2 MB

  pack_w_kernel<<<EMBED * KSEL / 256, 256, 0, stream>>>(W, sub, Wp, Wtp);
  gemm1_kernel<<<BATCH / 16, 256, 0, stream>>>(base, src, Wp, Tp);
  gemm2_kernel<<<(BATCH / 64) * 16, 256, 0, stream>>>(base, Tp, Wtp, out);
}